// Round 1
// 311.829 us; speedup vs baseline: 1.1193x; 1.1193x over previous
//
#include <hip/hip_runtime.h>
#include <cstdint>
#include <cstddef>

// Problem dims
#define Bz 8
#define Sz 128
#define Hz 768
#define Dz 256
#define Ez 50000
#define Mz (Bz*Sz)      // 1024
#define EPAD 50048      // 391 n-tiles * 128

// k_front role partitions
#define ENT_BLOCKS  12512   // EPAD/4 rows, 4 rows (waves) per block
#define CONV_BLOCKS 960     // 245760 float4s / 256
#define MD_BLOCKS   256     // 1024 rows, wave per row
#define FRONT_BLOCKS (ENT_BLOCKS + CONV_BLOCKS + MD_BLOCKS)

typedef __bf16 bf16x8 __attribute__((ext_vector_type(8)));
typedef float  f32x4  __attribute__((ext_vector_type(4)));

__device__ __forceinline__ unsigned short f2bf(float f) {
  unsigned int u = __float_as_uint(f);
  u += 0x7fffu + ((u >> 16) & 1u);   // round-to-nearest-even
  return (unsigned short)(u >> 16);
}

// async global->LDS, 16B per lane; LDS dest = wave-uniform base + lane*16
#define GLOAD_LDS16(gp, lp) \
  __builtin_amdgcn_global_load_lds((__attribute__((address_space(1))) void*)(gp), \
                                   (__attribute__((address_space(3))) void*)(lp), 16, 0, 0)

// ---------------------------------------------------------------- front kernel
// role 0 (blocks [0, ENT_BLOCKS)): entity row L2-normalize fp32->bf16, pad to EPAD
// role 1 (next CONV_BLOCKS):       convert hidden+W fp32->bf16
// role 2 (next MD_BLOCKS):         md logits GEMV, wave per (b,s) row -> lt[3][1024]
__global__ __launch_bounds__(256) void k_front(
    const float* __restrict__ hid, const float* __restrict__ W,
    const float* __restrict__ mdW, const float* __restrict__ mdb,
    const float* __restrict__ ent,
    ushort4* __restrict__ hb, ushort4* __restrict__ wb,
    ushort4* __restrict__ en, float* __restrict__ lt) {
  const int tid  = threadIdx.x;
  const int lane = tid & 63;
  const int wave = tid >> 6;
  int blk = blockIdx.x;

  if (blk < ENT_BLOCKS) {
    // ---- entity normalize: one wave per row
    int row = blk * 4 + wave;
    if (row >= Ez) {                      // zero padding rows [Ez, EPAD)
      en[(size_t)row*64 + lane] = make_ushort4(0,0,0,0);
      return;
    }
    float4 v = ((const float4*)ent)[(size_t)row*64 + lane];
    float ss = v.x*v.x + v.y*v.y + v.z*v.z + v.w*v.w;
    #pragma unroll
    for (int off = 32; off > 0; off >>= 1) ss += __shfl_xor(ss, off, 64);
    float inv = 1.f / fmaxf(sqrtf(ss), 1e-8f);
    ushort4 o;
    o.x = f2bf(v.x*inv); o.y = f2bf(v.y*inv); o.z = f2bf(v.z*inv); o.w = f2bf(v.w*inv);
    en[(size_t)row*64 + lane] = o;
    return;
  }
  blk -= ENT_BLOCKS;

  if (blk < CONV_BLOCKS) {
    // ---- fp32 -> bf16 convert: hidden (196608 float4) then W (49152 float4)
    int i = blk * 256 + tid;              // 0..245759 exact
    float4 v = (i < 196608) ? ((const float4*)hid)[i] : ((const float4*)W)[i - 196608];
    ushort4 o;
    o.x = f2bf(v.x); o.y = f2bf(v.y); o.z = f2bf(v.z); o.w = f2bf(v.w);
    if (i < 196608) hb[i] = o; else wb[i - 196608] = o;
    return;
  }
  blk -= CONV_BLOCKS;

  // ---- md logits: one wave per (b,s) row; 768 = 64 lanes * 3 float4
  int row = blk * 4 + wave;               // 0..1023
  const float4* hr = (const float4*)hid + (size_t)row*192 + lane*3;
  float4 a0 = hr[0], a1 = hr[1], a2 = hr[2];
  const float4* w4 = (const float4*)mdW;  // [3][192]
  float p[3];
  #pragma unroll
  for (int c = 0; c < 3; ++c) {
    float4 w0 = w4[c*192 + lane*3], w1 = w4[c*192 + lane*3 + 1], w2 = w4[c*192 + lane*3 + 2];
    p[c] = a0.x*w0.x + a0.y*w0.y + a0.z*w0.z + a0.w*w0.w
         + a1.x*w1.x + a1.y*w1.y + a1.z*w1.z + a1.w*w1.w
         + a2.x*w2.x + a2.y*w2.y + a2.z*w2.z + a2.w*w2.w;
  }
  #pragma unroll
  for (int c = 0; c < 3; ++c)
    #pragma unroll
    for (int off = 32; off > 0; off >>= 1) p[c] += __shfl_xor(p[c], off, 64);
  if (lane == 0) {
    #pragma unroll
    for (int c = 0; c < 3; ++c) lt[c*Mz + row] = p[c] + mdb[c];
  }
}

// ---------------------------------------------------------------- md log_softmax over seq axis
// grid = B*3 blocks, 128 threads (one per seq position)
__global__ void k_md_softmax(const float* __restrict__ lt, float* __restrict__ out) {
  int b = blockIdx.x / 3, c = blockIdx.x % 3;
  int s = threadIdx.x;
  float logit = lt[c*Mz + b*Sz + s];
  __shared__ float red[Sz];
  red[s] = logit; __syncthreads();
  for (int off = 64; off > 0; off >>= 1) {
    if (s < off) red[s] = fmaxf(red[s], red[s+off]);
    __syncthreads();
  }
  float mx = red[0]; __syncthreads();
  red[s] = expf(logit - mx); __syncthreads();
  for (int off = 64; off > 0; off >>= 1) {
    if (s < off) red[s] += red[s+off];
    __syncthreads();
  }
  float lse = mx + logf(red[0]);
  out[(size_t)(b*Sz + s)*3 + c] = logit - lse;
}

// ---------------------------------------------------------------- fused proj GEMM + tanh + rownorm
// proj = tanh(hidden @ W^T + b), then L2-normalize rows, write bf16.
// Tile 32x256 (full D per block so the row norm is block-local). Grid = 32 blocks
// (was 8x128-row blocks: only 8 CUs busy, latency-bound serial k-loop; 32 blocks
// quadruples latency hiding at identical structure).
// 4 waves: all share the 32 rows; wave w owns cols [w*64, w*64+64) (acc[2][4]).
__global__ __launch_bounds__(256, 1) void k_proj_norm(
    const unsigned short* __restrict__ A,   // hb [1024][768]
    const unsigned short* __restrict__ Bm,  // wb [256][768]
    const float* __restrict__ bias,         // [256]
    unsigned short* __restrict__ Pn) {      // [1024][256] bf16
  __shared__ unsigned short Alds[32*32];    // 2 KB
  __shared__ unsigned short Blds[256*32];   // 16 KB
  __shared__ float ssq[32][4];
  const int tid  = threadIdx.x;
  const int lane = tid & 63;
  const int wave = tid >> 6;
  const int m0 = blockIdx.x * 32;
  const int srow   = lane >> 2;
  const int schunk = lane & 3;
  const unsigned short* Agb = A  + (size_t)(m0 + srow)*Hz + schunk*8;
  const unsigned short* Bgb = Bm + (size_t)(wave*64 + srow)*Hz + schunk*8;

  f32x4 acc[2][4];
  f32x4 z = {0.f,0.f,0.f,0.f};
  #pragma unroll
  for (int i = 0; i < 2; ++i)
    #pragma unroll
    for (int j = 0; j < 4; ++j) acc[i][j] = z;

  const int kof = (lane >> 4) * 8;
  const int fr  = lane & 15;

  for (int kt = 0; kt < Hz; kt += 32) {
    if (wave == 0) {                       // A tile: 32 rows x 32 cols
      GLOAD_LDS16(Agb + kt,                 &Alds[0]);
      GLOAD_LDS16(Agb + 16*(size_t)Hz + kt, &Alds[16*32]);
    }
    #pragma unroll
    for (int c = 0; c < 4; ++c)            // B tile: wave w stages rows [w*64, w*64+64)
      GLOAD_LDS16(Bgb + c*16*(size_t)Hz + kt, &Blds[(wave*64 + c*16)*32]);
    __syncthreads();
    bf16x8 af[2], bq[4];
    #pragma unroll
    for (int mi = 0; mi < 2; ++mi)
      af[mi] = *(const bf16x8*)&Alds[(mi*16 + fr)*32 + kof];
    #pragma unroll
    for (int ni = 0; ni < 4; ++ni)
      bq[ni] = *(const bf16x8*)&Blds[(wave*64 + ni*16 + fr)*32 + kof];
    #pragma unroll
    for (int mi = 0; mi < 2; ++mi)
      #pragma unroll
      for (int ni = 0; ni < 4; ++ni)
        acc[mi][ni] = __builtin_amdgcn_mfma_f32_16x16x32_bf16(af[mi], bq[ni], acc[mi][ni], 0, 0, 0);
    __syncthreads();
  }

  // epilogue: tanh + bias, row sum-of-squares (16-lane shuffle + cross-wave LDS), normalize, bf16 store
  const int rl = (lane >> 4) * 4;          // row base within a 16-row fragment
  #pragma unroll
  for (int mi = 0; mi < 2; ++mi) {
    #pragma unroll
    for (int reg = 0; reg < 4; ++reg) {
      float s = 0.f;
      #pragma unroll
      for (int ni = 0; ni < 4; ++ni) {
        float v = tanhf(acc[mi][ni][reg] + bias[wave*64 + ni*16 + fr]);
        acc[mi][ni][reg] = v;
        s += v*v;
      }
      s += __shfl_xor(s, 1, 64); s += __shfl_xor(s, 2, 64);
      s += __shfl_xor(s, 4, 64); s += __shfl_xor(s, 8, 64);
      if ((lane & 15) == 0) ssq[mi*16 + rl + reg][wave] = s;
    }
  }
  __syncthreads();
  #pragma unroll
  for (int mi = 0; mi < 2; ++mi) {
    #pragma unroll
    for (int reg = 0; reg < 4; ++reg) {
      int r = mi*16 + rl + reg;
      float inv = 1.f / fmaxf(sqrtf(ssq[r][0] + ssq[r][1] + ssq[r][2] + ssq[r][3]), 1e-8f);
      #pragma unroll
      for (int ni = 0; ni < 4; ++ni)
        Pn[(size_t)(m0 + r)*Dz + wave*64 + ni*16 + fr] = f2bf(acc[mi][ni][reg] * inv);
    }
  }
}

// ---------------------------------------------------------------- similarity GEMM (NT, bf16 MFMA)
// C[m][n] = sum_k pn[m][k]*en[n][k]. 128x128 tile, 2x2 waves of 64x64, BK=32.
// 1D grid of 3128 = 8 XCD chunks x 391; bijective XCD swizzle (m204 form) so the
// 8 m-blocks sharing one en n-tile land on ONE XCD's L2 (en tile fetched once per
// L2 instead of 8x from L3). C stores are nontemporal: 204.8 MB streamed, never
// re-read -- keep it out of L2 while en/pn tiles are being shared.
__global__ __launch_bounds__(256) void k_sim(
    const unsigned short* __restrict__ A, const unsigned short* __restrict__ Bm,
    float* __restrict__ C) {
  __shared__ unsigned short Alds[128*32];
  __shared__ unsigned short Blds[128*32];
  const int tid  = threadIdx.x;
  const int lane = tid & 63;
  const int wave = tid >> 6;
  // bid -> (xcd = bid&7, q = bid>>3); work id w = xcd*391 + q covers [0,3128) bijectively.
  // w enumerates (n,m) with m fastest: 8 consecutive w (same XCD) share the n-tile.
  const int w  = (blockIdx.x & 7) * 391 + (blockIdx.x >> 3);
  const int m0 = (w & 7) * 128;
  const int n0 = (w >> 3) * 128;
  const int wm = (wave >> 1) * 64;
  const int wn = (wave & 1) * 64;
  const int srow   = lane >> 2;
  const int schunk = lane & 3;
  const unsigned short* Agb = A  + (size_t)(m0 + wave*32 + srow)*Dz + schunk*8;
  const unsigned short* Bgb = Bm + (size_t)(n0 + wave*32 + srow)*Dz + schunk*8;
  unsigned short* Al0 = &Alds[(wave*32)*32];
  unsigned short* Al1 = &Alds[(wave*32+16)*32];
  unsigned short* Bl0 = &Blds[(wave*32)*32];
  unsigned short* Bl1 = &Blds[(wave*32+16)*32];

  f32x4 acc[4][4];
  f32x4 z = {0.f,0.f,0.f,0.f};
  #pragma unroll
  for (int i = 0; i < 4; ++i)
    #pragma unroll
    for (int j = 0; j < 4; ++j) acc[i][j] = z;

  const int kof = (lane >> 4) * 8;
  const int fr  = lane & 15;

  for (int kt = 0; kt < Dz; kt += 32) {
    GLOAD_LDS16(Agb + kt,                 Al0);
    GLOAD_LDS16(Agb + 16*(size_t)Dz + kt, Al1);
    GLOAD_LDS16(Bgb + kt,                 Bl0);
    GLOAD_LDS16(Bgb + 16*(size_t)Dz + kt, Bl1);
    __syncthreads();
    bf16x8 af[4], bq[4];
    #pragma unroll
    for (int mi = 0; mi < 4; ++mi)
      af[mi] = *(const bf16x8*)&Alds[(wm + mi*16 + fr)*32 + kof];
    #pragma unroll
    for (int ni = 0; ni < 4; ++ni)
      bq[ni] = *(const bf16x8*)&Blds[(wn + ni*16 + fr)*32 + kof];
    #pragma unroll
    for (int mi = 0; mi < 4; ++mi)
      #pragma unroll
      for (int ni = 0; ni < 4; ++ni)
        acc[mi][ni] = __builtin_amdgcn_mfma_f32_16x16x32_bf16(af[mi], bq[ni], acc[mi][ni], 0, 0, 0);
    __syncthreads();
  }

  const int rbase = m0 + wm + (lane >> 4) * 4;
  const int cbase = n0 + wn + (lane & 15);
  #pragma unroll
  for (int mi = 0; mi < 4; ++mi) {
    #pragma unroll
    for (int ni = 0; ni < 4; ++ni) {
      int n = cbase + ni*16;
      if (n < Ez) {
        #pragma unroll
        for (int reg = 0; reg < 4; ++reg) {
          int m = rbase + mi*16 + reg;
          __builtin_nontemporal_store(acc[mi][ni][reg], &C[(size_t)m * Ez + n]);
        }
      }
    }
  }
}

// ---------------------------------------------------------------- launch
extern "C" void kernel_launch(void* const* d_in, const int* in_sizes, int n_in,
                              void* d_out, int out_size, void* d_ws, size_t ws_size,
                              hipStream_t stream) {
  (void)in_sizes; (void)n_in; (void)out_size; (void)ws_size;
  const float* hid = (const float*)d_in[0];
  const float* W   = (const float*)d_in[1];
  const float* bb  = (const float*)d_in[2];
  const float* mdW = (const float*)d_in[3];
  const float* mdb = (const float*)d_in[4];
  const float* ent = (const float*)d_in[5];
  float* out = (float*)d_out;

  char* ws = (char*)d_ws;
  unsigned short* hb = (unsigned short*)(ws);                 // [1024][768] bf16  1.5 MB
  unsigned short* wb = (unsigned short*)(ws + 1572864);       // [256][768]  bf16  384 KB
  unsigned short* pn = (unsigned short*)(ws + 1966080);       // [1024][256] bf16  512 KB
  float*          lt = (float*)         (ws + 2490368);       // [3][1024]   fp32  12 KB
  unsigned short* en = (unsigned short*)(ws + 2502656);       // [50048][256] bf16 25.6 MB

  k_front<<<FRONT_BLOCKS, 256, 0, stream>>>(hid, W, mdW, mdb, ent,
                                            (ushort4*)hb, (ushort4*)wb, (ushort4*)en, lt);
  k_md_softmax<<<Bz*3, Sz, 0, stream>>>(lt, out);
  k_proj_norm<<<32, 256, 0, stream>>>(hb, wb, bb, pn);
  k_sim<<<3128, 256, 0, stream>>>(pn, en, out + (size_t)Mz*3);
}